// Round 3
// baseline (236.685 us; speedup 1.0000x reference)
//
#include <hip/hip_runtime.h>

// out[2i]   = x[2i]
// out[2i+1] = x[2i+1] - x[2i] / 50
// Pure elementwise on adjacent pairs -> memory-bound streaming kernel.
//
// Round-1 lesson (kept): all indexing derives from out_size only (in_sizes[0]
// previously caused OOB writes that clobbered the harness's pristine copy).
//
// Round-2 post-mortem: nontemporal stores + un-unrolled grid-stride loop ran
// at 2.4 TB/s (84.6 us) -- LATENCY-bound: 16 serial iterations/lane, one
// outstanding load each, and nt stores bypass L2's write-combining (the
// harness fill hits 6.5 TB/s with NORMAL stores). Both reverted/fixed here:
//  - normal stores (through L2)
//  - 4-way manual unroll: 4 independent float4 loads in flight per lane
//    before any compute/store -> 4x memory-level parallelism.
// Grid stays 2048 blocks (8/CU): n4 / (2048*256) = 16 -> exactly 4 unrolled
// iterations, remainder loop for generality.

__global__ __launch_bounds__(256) void dn_kernel(const float4* __restrict__ in,
                                                 float4* __restrict__ out,
                                                 int n4) {
    const int stride = gridDim.x * blockDim.x;
    int i = blockIdx.x * blockDim.x + threadIdx.x;

    for (; i + 3 * stride < n4; i += 4 * stride) {
        // Issue all 4 loads first -> 4 outstanding vmem ops per lane.
        float4 v0 = in[i];
        float4 v1 = in[i + stride];
        float4 v2 = in[i + 2 * stride];
        float4 v3 = in[i + 3 * stride];

        float4 r0, r1, r2, r3;
        r0.x = v0.x; r0.y = v0.y - v0.x * (1.0f / 50.0f);
        r0.z = v0.z; r0.w = v0.w - v0.z * (1.0f / 50.0f);
        r1.x = v1.x; r1.y = v1.y - v1.x * (1.0f / 50.0f);
        r1.z = v1.z; r1.w = v1.w - v1.z * (1.0f / 50.0f);
        r2.x = v2.x; r2.y = v2.y - v2.x * (1.0f / 50.0f);
        r2.z = v2.z; r2.w = v2.w - v2.z * (1.0f / 50.0f);
        r3.x = v3.x; r3.y = v3.y - v3.x * (1.0f / 50.0f);
        r3.z = v3.z; r3.w = v3.w - v3.z * (1.0f / 50.0f);

        out[i] = r0;
        out[i + stride] = r1;
        out[i + 2 * stride] = r2;
        out[i + 3 * stride] = r3;
    }
    // Remainder (not taken for the expected shape, kept for generality).
    for (; i < n4; i += stride) {
        float4 v = in[i];
        float4 r;
        r.x = v.x; r.y = v.y - v.x * (1.0f / 50.0f);
        r.z = v.z; r.w = v.w - v.z * (1.0f / 50.0f);
        out[i] = r;
    }
}

// Scalar tail in case out_size is not a multiple of 4 (not expected here,
// but keeps the kernel fully general without relying on in_sizes).
__global__ void dn_tail_kernel(const float* __restrict__ in,
                               float* __restrict__ out,
                               int start, int n) {
    int i = start + blockIdx.x * blockDim.x + threadIdx.x;
    if (i < n) {
        float v = in[i];
        if (i & 1) {
            out[i] = v - in[i - 1] * (1.0f / 50.0f);
        } else {
            out[i] = v;
        }
    }
}

extern "C" void kernel_launch(void* const* d_in, const int* in_sizes, int n_in,
                              void* d_out, int out_size, void* d_ws, size_t ws_size,
                              hipStream_t stream) {
    const float* in = (const float*)d_in[0];
    float* out = (float*)d_out;
    int n = out_size;             // 128*64*64*64 = 33,554,432 fp32 elements
    int n4 = n / 4;               // float4 count: 8,388,608
    if (n4 > 0) {
        int block = 256;
        int grid = (n4 + block - 1) / block;
        if (grid > 2048) grid = 2048;   // 8 blocks/CU * 256 CUs; 4x-unrolled grid-stride covers the rest
        dn_kernel<<<grid, block, 0, stream>>>((const float4*)in, (float4*)out, n4);
    }
    int tail_start = n4 * 4;
    int tail = n - tail_start;
    if (tail > 0) {
        dn_tail_kernel<<<1, 64, 0, stream>>>(in, out, tail_start, n);
    }
}

// Round 4
// 230.442 us; speedup vs baseline: 1.0271x; 1.0271x over previous
//
#include <hip/hip_runtime.h>

// out[2i]   = x[2i]
// out[2i+1] = x[2i+1] - x[2i] / 50
// Pure elementwise on adjacent pairs -> memory-bound streaming kernel.
//
// Round-1 lesson (kept): all indexing derives from out_size only (in_sizes[0]
// previously caused OOB writes that clobbered the harness's pristine copy).
//
// Round-2/3 post-mortem: grid-stride @2048 blocks = 84.5 us REGARDLESS of
// per-lane ILP (1x vs 4x identical) or store type (nt vs normal identical).
// Round-0's one-shot 32768-block kernel was ~57-68 us (fastest structure).
// Model: read BW is capped by per-CU outstanding-request capacity x latency;
// aggregate concurrency scales with RESIDENT WAVES (one-shot keeps occupancy
// ~full; grid-stride measured only ~50%), not per-wave unroll at low occ.
//
// Round-4: one-shot grid (no loop) + 2 independent float4 loads per lane
// issued back-to-back (split-half indexing, both streams coalesced), doubling
// in-flight read lines per CU at full occupancy. 16384 blocks x 256 threads.

__global__ __launch_bounds__(256) void dn_kernel(const float4* __restrict__ in,
                                                 float4* __restrict__ out,
                                                 int half) {
    int t = blockIdx.x * blockDim.x + threadIdx.x;
    if (t < half) {
        // Two independent, individually-coalesced streams; both loads issue
        // before either store -> 2 outstanding 1KB wave-loads.
        float4 v0 = in[t];
        float4 v1 = in[t + half];

        float4 r0, r1;
        r0.x = v0.x; r0.y = v0.y - v0.x * (1.0f / 50.0f);
        r0.z = v0.z; r0.w = v0.w - v0.z * (1.0f / 50.0f);
        r1.x = v1.x; r1.y = v1.y - v1.x * (1.0f / 50.0f);
        r1.z = v1.z; r1.w = v1.w - v1.z * (1.0f / 50.0f);

        out[t] = r0;
        out[t + half] = r1;
    }
}

// Scalar tail for anything not covered by the paired-float4 main kernel
// (odd n4 leftover float4 and/or n % 4 remainder floats). Not taken for the
// expected shape (n4 = 8,388,608 even, n % 4 == 0); kept for generality.
__global__ void dn_tail_kernel(const float* __restrict__ in,
                               float* __restrict__ out,
                               int start, int n) {
    int i = start + blockIdx.x * blockDim.x + threadIdx.x;
    if (i < n) {
        float v = in[i];
        if (i & 1) {
            out[i] = v - in[i - 1] * (1.0f / 50.0f);
        } else {
            out[i] = v;
        }
    }
}

extern "C" void kernel_launch(void* const* d_in, const int* in_sizes, int n_in,
                              void* d_out, int out_size, void* d_ws, size_t ws_size,
                              hipStream_t stream) {
    const float* in = (const float*)d_in[0];
    float* out = (float*)d_out;
    int n = out_size;             // 128*64*64*64 = 33,554,432 fp32 elements
    int n4 = n / 4;               // float4 count: 8,388,608
    int half = n4 / 2;            // 4,194,304 -> one thread per float4-pair
    if (half > 0) {
        int block = 256;
        int grid = (half + block - 1) / block;   // 16384 blocks, one-shot
        dn_kernel<<<grid, block, 0, stream>>>((const float4*)in, (float4*)out, half);
    }
    int tail_start = (half * 2) * 4;  // covered: [0, 2*half) float4s
    int tail = n - tail_start;
    if (tail > 0) {
        int block = 64;
        int grid = (tail + block - 1) / block;
        dn_tail_kernel<<<grid, block, 0, stream>>>(in, out, tail_start, n);
    }
}

// Round 5
// 216.921 us; speedup vs baseline: 1.0911x; 1.0623x over previous
//
#include <hip/hip_runtime.h>

// out[2i]   = x[2i]
// out[2i+1] = x[2i+1] - x[2i] / 50
// Pure elementwise on adjacent pairs -> memory-bound. float4 = two pairs per
// lane, coalesced 16B/lane. One-shot grid, one float4 per thread.
//
// Round-1 lesson (kept): all indexing derives from out_size only (in_sizes[0]
// previously caused OOB writes that clobbered the harness's pristine copy).
//
// Rounds 2-4 post-mortem (why this is deliberately the simple version):
//  - nt-stores, 2x/4x per-lane ILP, grid-stride @2048, one-shot @16384 all
//    measured NEUTRAL-to-WORSE vs this structure (timed residual 57 us here
//    vs 66-72 us for every variant). Profiled BW is pinned at ~2.45 TB/s
//    HBM-side with VALUBusy ~1.5% regardless of CU-side structure: the limit
//    is outside the CU (timed-run contention with the harness re-poison
//    fill's 536 MB L2->HBM write drain, plus mixed R/W stream turnaround).
//  - Timed region also contains ~164 us of harness fills we don't own.
// Conclusion: one-shot 32768x256 with a single float4 per lane is the
// empirical best; CU-side "optimizations" only add overhead here.

__global__ __launch_bounds__(256) void dn_kernel(const float4* __restrict__ in,
                                                 float4* __restrict__ out,
                                                 int n4) {
    int i = blockIdx.x * blockDim.x + threadIdx.x;
    if (i < n4) {
        float4 v = in[i];
        float4 r;
        r.x = v.x;
        r.y = v.y - v.x * (1.0f / 50.0f);
        r.z = v.z;
        r.w = v.w - v.z * (1.0f / 50.0f);
        out[i] = r;
    }
}

// Scalar tail in case out_size is not a multiple of 4 (not expected here,
// but keeps the kernel fully general without relying on in_sizes).
__global__ void dn_tail_kernel(const float* __restrict__ in,
                               float* __restrict__ out,
                               int start, int n) {
    int i = start + blockIdx.x * blockDim.x + threadIdx.x;
    if (i < n) {
        float v = in[i];
        if (i & 1) {
            out[i] = v - in[i - 1] * (1.0f / 50.0f);
        } else {
            out[i] = v;
        }
    }
}

extern "C" void kernel_launch(void* const* d_in, const int* in_sizes, int n_in,
                              void* d_out, int out_size, void* d_ws, size_t ws_size,
                              hipStream_t stream) {
    const float* in = (const float*)d_in[0];
    float* out = (float*)d_out;
    int n = out_size;             // 128*64*64*64 = 33,554,432 fp32 elements
    int n4 = n / 4;               // float4 count: 8,388,608
    if (n4 > 0) {
        int block = 256;
        int grid = (n4 + block - 1) / block;   // 32768 blocks, one-shot
        dn_kernel<<<grid, block, 0, stream>>>((const float4*)in, (float4*)out, n4);
    }
    int tail_start = n4 * 4;
    int tail = n - tail_start;
    if (tail > 0) {
        dn_tail_kernel<<<1, 64, 0, stream>>>(in, out, tail_start, n);
    }
}